// Round 3
// baseline (353.531 us; speedup 1.0000x reference)
//
#include <hip/hip_runtime.h>

// Problem constants
static constexpr int   Cc  = 21;
static constexpr int   HWn = 512 * 512;         // 262144 = 2^18
static constexpr int   Nn  = 8 * HWn;           // 2097152 pixels
static constexpr float MAXM  = 0.5f;
static constexpr float Sc    = 30.0f;
static constexpr float LOG2E = 1.4426950408889634f;
static constexpr float LN2   = 0.6931471805599453f;

static constexpr int HIST_BLOCKS = 512;               // 512 blk * 256 thr * 4 int4 = Nn/4
static constexpr int LOSS_BLOCKS = 2048;
static constexpr int LOSS_ITERS  = 4;
static constexpr int CHUNK       = Nn / LOSS_ITERS;   // 524288 pixels per chunk

// ws layout (bytes): 0: int counts[21] ; 96: uint done-flag ; 128: double partial[2048]
static constexpr int WS_COUNTS = 0;
static constexpr int WS_FLAG   = 96;
static constexpr int WS_PART   = 128;

// ---------------------------------------------------------------------------
// K1: class histogram. 512 blocks (4 int4 per thread). Per-WAVE LDS
// sub-histograms cut same-address LDS atomic serialization 4x; then 21
// global atomics per block.
__global__ __launch_bounds__(256) void hist_kernel(const int4* __restrict__ t4,
                                                   int* __restrict__ counts) {
    __shared__ int lh[4][Cc];
    int t = threadIdx.x;
    if (t < 4 * Cc) ((int*)lh)[t] = 0;
    __syncthreads();
    int wave = t >> 6;
    int base = blockIdx.x * (256 * 4) + t;
    #pragma unroll
    for (int i = 0; i < 4; ++i) {
        int4 v = t4[base + i * 256];
        atomicAdd(&lh[wave][v.x], 1);
        atomicAdd(&lh[wave][v.y], 1);
        atomicAdd(&lh[wave][v.z], 1);
        atomicAdd(&lh[wave][v.w], 1);
    }
    __syncthreads();
    if (t < Cc)
        atomicAdd(&counts[t], lh[0][t] + lh[1][t] + lh[2][t] + lh[3][t]);
}

// ---------------------------------------------------------------------------
// K2: main loss. ONE scalar pixel per thread per iteration: x[21] floats =
// 21 data VGPRs, all live until pass 2 -> compiler MUST keep 21 loads in
// flight (MLP=21 by liveness; round-2's online variant collapsed to VGPR=24
// / MLP~2 / 157us). Outer grid-stride loop (4 chunks) is `unroll 1` so the
// tile never fuses to 84 regs. Two-pass register math identical to the
// verified round-0 kernel (absmax 0). launch_bounds(256,6): VGPR cap 85,
// ~75% occupancy. m_list per-wave from L2-hot counts; plain-store partials
// + fenced last-block-done final mean. No barrier anywhere in the hot path.
__global__ __launch_bounds__(256, 6) void loss_kernel(const float* __restrict__ pred,
                                                      const int* __restrict__ target,
                                                      const int* __restrict__ counts,
                                                      double* __restrict__ partial,
                                                      unsigned int* __restrict__ flag,
                                                      float* __restrict__ out) {
    __shared__ double wsum[4];
    __shared__ bool   s_last;
    int t    = threadIdx.x;
    int lane = t & 63;

    // per-wave m_list: smv = S*log2e * m_list[c] held in lane c (c < 21)
    float mval = 0.0f;
    if (lane < Cc) {
        float cnt = (float)counts[lane] + 1e-4f;
        mval = 1.0f / sqrtf(sqrtf(cnt));      // x^-0.25, same expr as reference
    }
    float mxm = mval;
    #pragma unroll
    for (int o = 32; o >= 1; o >>= 1) mxm = fmaxf(mxm, __shfl_down(mxm, o));
    mxm = __shfl(mxm, 0);
    float smv = Sc * LOG2E * mval * (MAXM / mxm);

    const float S2 = Sc * LOG2E;
    int tid = blockIdx.x * 256 + t;           // [0, 512K)
    float nll2 = 0.0f;

    #pragma unroll 1
    for (int it = 0; it < LOSS_ITERS; ++it) {
        int n  = tid + it * CHUNK;            // [0, Nn)
        int b  = n >> 18;                     // HWn = 2^18
        int hw = n & (HWn - 1);
        const float* p = pred + (size_t)b * (Cc * HWn) + hw;

        // 21 independent coalesced dword loads — all live => all in flight
        float x[Cc];
        #pragma unroll
        for (int c = 0; c < Cc; ++c) x[c] = p[c * HWn];

        int   y   = target[n];
        float smy = __shfl(smv, y);

        // pass 1: max + target value (base-2 logits)
        float mx = -1e30f, vy = 0.0f;
        #pragma unroll
        for (int c = 0; c < Cc; ++c) {
            bool  isy = (c == y);
            float val = fmaf(S2, x[c], isy ? -smy : 0.0f);
            mx = fmaxf(mx, val);
            vy = isy ? val : vy;
        }

        // pass 2: sum of exp2 recomputed from registers
        float cb = -mx, cy = -smy - mx;
        float sum = 0.0f;
        #pragma unroll
        for (int c = 0; c < Cc; ++c)
            sum += exp2f(fmaf(S2, x[c], (c == y) ? cy : cb));

        nll2 += __log2f(sum) + mx - vy;
    }
    float nll = nll2 * LN2;

    // wave (64-lane) reduce
    #pragma unroll
    for (int o = 32; o >= 1; o >>= 1) nll += __shfl_down(nll, o);

    int wave = t >> 6;
    if ((t & 63) == 0) wsum[wave] = (double)nll;
    __syncthreads();
    if (t == 0) {
        double bsum = wsum[0] + wsum[1] + wsum[2] + wsum[3];
        partial[blockIdx.x] = bsum;           // plain store, no contention
        __threadfence();                      // release partial before flag bump
        unsigned done = atomicAdd(flag, 1u);
        s_last = (done == (unsigned)(LOSS_BLOCKS - 1));
    }
    __syncthreads();

    if (s_last) {
        __threadfence();                      // acquire other blocks' partials
        double sm = 0.0;
        for (int i = t; i < LOSS_BLOCKS; i += 256) sm += partial[i];
        #pragma unroll
        for (int o = 32; o >= 1; o >>= 1) sm += __shfl_down(sm, o);
        if ((t & 63) == 0) wsum[t >> 6] = sm;
        __syncthreads();
        if (t == 0)
            out[0] = (float)((wsum[0] + wsum[1] + wsum[2] + wsum[3]) / (double)Nn);
    }
}

extern "C" void kernel_launch(void* const* d_in, const int* in_sizes, int n_in,
                              void* d_out, int out_size, void* d_ws, size_t ws_size,
                              hipStream_t stream) {
    const float* pred   = (const float*)d_in[0];
    const int*   target = (const int*)d_in[1];
    float*       out    = (float*)d_out;

    char* ws = (char*)d_ws;
    int*          counts  = (int*)(ws + WS_COUNTS);
    unsigned int* flag    = (unsigned int*)(ws + WS_FLAG);
    double*       partial = (double*)(ws + WS_PART);

    hipMemsetAsync(d_ws, 0, 128, stream);     // zero counts + done-flag

    hist_kernel <<<HIST_BLOCKS, 256, 0, stream>>>((const int4*)target, counts);
    loss_kernel <<<LOSS_BLOCKS, 256, 0, stream>>>(pred, target,
                                                  counts, partial, flag, out);
}